// Round 13
// baseline (320.359 us; speedup 1.0000x reference)
//
#include <hip/hip_runtime.h>
#include <stdint.h>

// ---------------------------------------------------------------------------
// FlatLinear: y = x @ W^T + bias, W = centroids[labels] (4096x4096, K=256 cb)
// M=8192, N=4096, K=4096.  dequant W->bf16, cast x->bf16, then MFMA GEMM.
// R14: exact R6 champion (best measured: 319.9 us total, gemm ~280 us,
// MfmaUtil 45%, 0 bank conflicts, 2 blocks/CU) with s_setprio REMOVED from
// the MFMA cluster (T5 is null-to-negative on lockstep 2-phase GEMM, m190).
// NT stores reverted (R12: WRITE_SIZE 131->162 MB, slight regression).
// ---------------------------------------------------------------------------

typedef __attribute__((ext_vector_type(8))) short  bf16x8;
typedef __attribute__((ext_vector_type(4))) float  f32x4;
typedef __attribute__((ext_vector_type(4))) int    i32x4;
typedef __attribute__((ext_vector_type(8))) ushort u16x8;
typedef __attribute__((ext_vector_type(4))) float  fvec4;

#define K_DIM 4096
#define N_DIM 4096
#define NSTEP (K_DIM / 32)   // 128 K-steps of BK=32

__device__ __forceinline__ ushort f2bf(float f) {
  uint32_t u = __float_as_uint(f);
  return (ushort)((u + 0x7fffu + ((u >> 16) & 1u)) >> 16);
}

__device__ __forceinline__ void async16(const ushort* g, ushort* l) {
  __builtin_amdgcn_global_load_lds(
      (const __attribute__((address_space(1))) void*)g,
      (__attribute__((address_space(3))) void*)l, 16, 0, 0);
}

// --------------------------- dequant: labels -> bf16 W ---------------------
__global__ __launch_bounds__(256) void dequant_w(const int* __restrict__ labels,
                                                 const float* __restrict__ cent,
                                                 ushort* __restrict__ wb, int n) {
  __shared__ ushort cb[256];
  cb[threadIdx.x] = f2bf(cent[threadIdx.x]);
  __syncthreads();
  const int stride = gridDim.x * 256 * 8;
  for (int i = ((int)blockIdx.x * 256 + (int)threadIdx.x) * 8; i < n; i += stride) {
    i32x4 l0 = *(const i32x4*)(labels + i);
    i32x4 l1 = *(const i32x4*)(labels + i + 4);
    u16x8 w;
    w[0] = cb[l0[0]]; w[1] = cb[l0[1]]; w[2] = cb[l0[2]]; w[3] = cb[l0[3]];
    w[4] = cb[l1[0]]; w[5] = cb[l1[1]]; w[6] = cb[l1[2]]; w[7] = cb[l1[3]];
    *(u16x8*)(wb + i) = w;
  }
}

// --------------------------- cast: x fp32 -> bf16 ---------------------------
__global__ __launch_bounds__(256) void cvt_x(const float* __restrict__ x,
                                             ushort* __restrict__ xb, int n) {
  const int stride = gridDim.x * 256 * 8;
  for (int i = ((int)blockIdx.x * 256 + (int)threadIdx.x) * 8; i < n; i += stride) {
    fvec4 a = *(const fvec4*)(x + i);
    fvec4 b = *(const fvec4*)(x + i + 4);
    u16x8 w;
    w[0] = f2bf(a[0]); w[1] = f2bf(a[1]); w[2] = f2bf(a[2]); w[3] = f2bf(a[3]);
    w[4] = f2bf(b[0]); w[5] = f2bf(b[1]); w[6] = f2bf(b[2]); w[7] = f2bf(b[3]);
    *(u16x8*)(xb + i) = w;
  }
}

// --------------------------- 256x128-tile bf16 GEMM -------------------------
// C[M][N] = A[M][K] * B[N][K]^T + bias.
// Tile 256x128, BK=32, 512 threads = 8 waves (4M x 2N), wave out = 64x64.
// LDS per buffer: A [256][32] (8192 ushort) + B [128][32] (4096 ushort), x2.
// Staging: 3 async16/thread/step; wave-uniform LDS dest (HW adds lane*16B);
// source pre-swizzled unit ^= ((row>>1)&3); reads use the same XOR
// (measured 0 conflicts). Per step: frags(buf b), 16 MFMA, vmcnt(0),
// s_barrier. 2 blocks/CU desync hides the drain.
__global__ __launch_bounds__(512, 4) void gemm2(const ushort* __restrict__ A,
                                                const ushort* __restrict__ B,
                                                const float* __restrict__ bias,
                                                float* __restrict__ C) {
  __shared__ ushort As[2][8192];   // [buf][256 rows x 32]
  __shared__ ushort Bs[2][4096];   // [buf][128 rows x 32]

  const int tid  = threadIdx.x;
  const int wid  = tid >> 6;
  const int lane = tid & 63;
  const int wm = wid >> 1, wn = wid & 1;
  const int l15 = lane & 15;

  // bijective XCD-aware swizzle (m204)
  const int nwg = gridDim.x, bid = blockIdx.x;
  const int q = nwg >> 3, r = nwg & 7;
  const int xcd = bid & 7, sub = bid >> 3;
  const int swz = (xcd < r ? xcd * (q + 1) : r * (q + 1) + (xcd - r) * q) + sub;
  const int gn = N_DIM / 128;          // 32
  const int bm = swz / gn, bn = swz % gn;

  // ---- staging: thread tid loads unit tid of A-low (rows 0..127), unit tid
  // of A-high (rows 128..255, LDS elem 4096+), unit tid of B (rows 0..127).
  // unit = 8 ushorts; row = tid>>2; src elem pre-swizzled by ((row>>1)&3)<<3
  // (row+128 keeps the same swizzle: 128>>1 = 64 == 0 mod 4).
  const int srow = tid >> 2;
  const int seu  = ((tid & 3) * 8) ^ (((srow >> 1) & 3) << 3);
  const ushort* gA0 = A + (size_t)(bm * 256 + srow) * K_DIM + seu;
  const ushort* gA1 = gA0 + (size_t)128 * K_DIM;
  const ushort* gB  = B + (size_t)(bn * 128 + srow) * K_DIM + seu;
  const int wbase = wid * 512;  // wave-uniform LDS unit base (64 lanes x 8)

  // ---- fragment read offsets (read-side XOR matches store swizzle):
  //   unit = (lane>>4) ^ ((row>>1)&3), row = <mult of 16> + l15
  const int esw  = ((lane >> 4) * 8) ^ (((l15 >> 1) & 3) << 3);
  const int aOff = (wm * 64 + l15) * 32 + esw;
  const int bOff = (wn * 64 + l15) * 32 + esw;

  f32x4 acc[4][4];
#pragma unroll
  for (int i = 0; i < 4; ++i)
#pragma unroll
    for (int j = 0; j < 4; ++j) acc[i][j] = (f32x4){0.f, 0.f, 0.f, 0.f};

  bf16x8 af[4], bfr[4];

#define STAGE_(b, kt)                               \
  do {                                              \
    async16(gA0 + (kt), &As[b][wbase]);             \
    async16(gA1 + (kt), &As[b][4096 + wbase]);      \
    async16(gB + (kt), &Bs[b][wbase]);              \
  } while (0)
#define LDFRAG_(b)                                                   \
  do {                                                               \
    _Pragma("unroll") for (int m_ = 0; m_ < 4; ++m_)                 \
        af[m_] = *(const bf16x8*)&As[b][aOff + m_ * 512];            \
    _Pragma("unroll") for (int n_ = 0; n_ < 4; ++n_)                 \
        bfr[n_] = *(const bf16x8*)&Bs[b][bOff + n_ * 512];           \
  } while (0)
#define MM_()                                                        \
  do {                                                               \
    _Pragma("unroll") for (int m_ = 0; m_ < 4; ++m_)                 \
        _Pragma("unroll") for (int n_ = 0; n_ < 4; ++n_)             \
            acc[m_][n_] = __builtin_amdgcn_mfma_f32_16x16x32_bf16(   \
                af[m_], bfr[n_], acc[m_][n_], 0, 0, 0);              \
  } while (0)
#define VMW0 asm volatile("s_waitcnt vmcnt(0)" ::: "memory")
#define BAR  __builtin_amdgcn_s_barrier()

  // prologue: stage step 0 into buf 0
  STAGE_(0, 0);
  VMW0;
  BAR;

  // 127 pipelined steps: 63 x (buf0, buf1) + 1 x buf0; tail reads buf1.
  for (int t = 0; t < NSTEP - 2; t += 2) {
    STAGE_(1, (t + 1) * 32);
    LDFRAG_(0); MM_();
    VMW0; BAR;
    STAGE_(0, (t + 2) * 32);
    LDFRAG_(1); MM_();
    VMW0; BAR;
  }
  STAGE_(1, (NSTEP - 1) * 32);
  LDFRAG_(0); MM_();
  VMW0; BAR;
  LDFRAG_(1); MM_();

#undef STAGE_
#undef LDFRAG_
#undef MM_
#undef VMW0
#undef BAR

  // C write: C/D layout col = lane&15, row = (lane>>4)*4 + reg
  float bb[4];
#pragma unroll
  for (int n = 0; n < 4; ++n) bb[n] = bias[bn * 128 + wn * 64 + n * 16 + l15];

  float* Cp = C + (size_t)(bm * 256 + wm * 64) * N_DIM + bn * 128 + wn * 64;
  const int rbase = (lane >> 4) * 4;
#pragma unroll
  for (int mi = 0; mi < 4; ++mi)
#pragma unroll
    for (int rr = 0; rr < 4; ++rr) {
      float* cr = Cp + (size_t)(mi * 16 + rbase + rr) * N_DIM;
#pragma unroll
      for (int n = 0; n < 4; ++n)
        cr[n * 16 + l15] = acc[mi][n][rr] + bb[n];
    }
}

// --------------------------- naive fallback (ws too small) ------------------
__global__ void naive_kernel(const float* __restrict__ x,
                             const float* __restrict__ cent,
                             const int* __restrict__ labels,
                             const float* __restrict__ bias,
                             float* __restrict__ out, int M) {
  __shared__ float cb[256];
  if (threadIdx.x < 256) cb[threadIdx.x] = cent[threadIdx.x];
  __syncthreads();
  long o = (long)blockIdx.x * blockDim.x + threadIdx.x;
  if (o >= (long)M * N_DIM) return;
  int n = (int)(o % N_DIM);
  long m = o / N_DIM;
  const float* xr = x + m * K_DIM;
  const int* lr = labels + (long)n * K_DIM;
  float s = 0.f;
  for (int k = 0; k < K_DIM; ++k) s += xr[k] * cb[lr[k]];
  out[o] = s + bias[n];
}

// ---------------------------------------------------------------------------
extern "C" void kernel_launch(void* const* d_in, const int* in_sizes, int n_in,
                              void* d_out, int out_size, void* d_ws, size_t ws_size,
                              hipStream_t stream) {
  const float* x      = (const float*)d_in[0];
  const float* cent   = (const float*)d_in[1];
  const int*   labels = (const int*)d_in[2];
  const float* bias   = (const float*)d_in[3];
  float* out = (float*)d_out;

  const int xN = in_sizes[0];      // M*K
  const int M  = xN / K_DIM;       // 8192
  const int wN = in_sizes[2];      // N*K

  const size_t need = (size_t)wN * 2 + (size_t)xN * 2;  // 96 MB
  if (ws_size < need || (M % 256) != 0) {
    long total = (long)M * N_DIM;
    int blocks = (int)((total + 255) / 256);
    naive_kernel<<<blocks, 256, 0, stream>>>(x, cent, labels, bias, out, M);
    return;
  }

  ushort* wb = (ushort*)d_ws;      // [N][K] bf16
  ushort* xb = wb + (size_t)wN;    // [M][K] bf16

  dequant_w<<<2048, 256, 0, stream>>>(labels, cent, wb, wN);
  cvt_x<<<2048, 256, 0, stream>>>(x, xb, xN);

  const int grid = (M / 256) * (N_DIM / 128);  // 1024
  gemm2<<<grid, 512, 0, stream>>>(xb, wb, bias, out);
}

// Round 14
// 198.823 us; speedup vs baseline: 1.6113x; 1.6113x over previous
//
#include <hip/hip_runtime.h>
#include <stdint.h>

// ---------------------------------------------------------------------------
// FlatLinear: y = x @ W^T + bias, W = centroids[labels] (4096x4096, K=256 cb)
// M=8192, N=4096, K=4096.
// R14: INT8 port of the R6 champion. Same 256x128 tile, same 2-phase
// schedule, same LDS byte-geometry and swizzle (measured 0 conflicts), but
// mfma_i32_16x16x64_i8 doubles K per step (BK=64 bytes) -> NSTEP 128->64.
// Per-row x scales + per-tensor W scale; i32 accumulation is exact.
// Predicted absmax ~4-5 (threshold 7.16). If fail -> revert to champion.
// ---------------------------------------------------------------------------

typedef __attribute__((ext_vector_type(4))) int    i32x4;
typedef __attribute__((ext_vector_type(4))) float  fvec4;

#define K_DIM 4096
#define N_DIM 4096
#define NSTEP (K_DIM / 64)   // 64 K-steps of 64 int8

__device__ __forceinline__ void async16(const void* g, void* l) {
  __builtin_amdgcn_global_load_lds(
      (const __attribute__((address_space(1))) void*)g,
      (__attribute__((address_space(3))) void*)l, 16, 0, 0);
}

// ---------------- quant W: labels -> int8 via codebook, per-tensor scale ----
__global__ __launch_bounds__(256) void quant_w(const int* __restrict__ labels,
                                               const float* __restrict__ cent,
                                               char* __restrict__ wq,
                                               float* __restrict__ swp, int n) {
  __shared__ float red[256];
  __shared__ char cb[256];
  const int t = threadIdx.x;
  const float c = cent[t];
  red[t] = fabsf(c);
  __syncthreads();
  for (int s = 128; s > 0; s >>= 1) {
    if (t < s) red[t] = fmaxf(red[t], red[t + s]);
    __syncthreads();
  }
  const float m = fmaxf(red[0], 1e-20f);
  cb[t] = (char)(int)rintf(c * (127.f / m));
  if (blockIdx.x == 0 && t == 0) *swp = m / 127.f;
  __syncthreads();
  const int stride = gridDim.x * 256 * 16;
  for (int i = ((int)blockIdx.x * 256 + t) * 16; i < n; i += stride) {
    int out[4];
#pragma unroll
    for (int j = 0; j < 4; ++j) {
      i32x4 l = *(const i32x4*)(labels + i + j * 4);
      out[j] = (cb[l[0]] & 255) | ((cb[l[1]] & 255) << 8) |
               ((cb[l[2]] & 255) << 16) | ((cb[l[3]] & 255) << 24);
    }
    *(i32x4*)(wq + i) = *(i32x4*)out;
  }
}

// ---------------- quant x: per-row max -> int8 + per-row scale --------------
__global__ __launch_bounds__(256) void quant_x(const float* __restrict__ x,
                                               char* __restrict__ xq,
                                               float* __restrict__ sx) {
  __shared__ float red[256];
  const int row = blockIdx.x;
  const float* xr = x + (size_t)row * K_DIM;
  const int t = threadIdx.x;
  fvec4 v[4];
  float mx = 0.f;
#pragma unroll
  for (int j = 0; j < 4; ++j) {
    v[j] = *(const fvec4*)(xr + t * 16 + j * 4);
#pragma unroll
    for (int e = 0; e < 4; ++e) mx = fmaxf(mx, fabsf(v[j][e]));
  }
  red[t] = mx;
  __syncthreads();
  for (int s = 128; s > 0; s >>= 1) {
    if (t < s) red[t] = fmaxf(red[t], red[t + s]);
    __syncthreads();
  }
  const float m = fmaxf(red[0], 1e-20f);
  const float inv = 127.f / m;
  if (t == 0) sx[row] = m / 127.f;
  int out[4];
#pragma unroll
  for (int j = 0; j < 4; ++j) {
    const int q0 = (int)rintf(v[j][0] * inv), q1 = (int)rintf(v[j][1] * inv);
    const int q2 = (int)rintf(v[j][2] * inv), q3 = (int)rintf(v[j][3] * inv);
    out[j] = (q0 & 255) | ((q1 & 255) << 8) | ((q2 & 255) << 16) |
             ((q3 & 255) << 24);
  }
  *(i32x4*)(xq + (size_t)row * K_DIM + t * 16) = *(i32x4*)out;
}

// --------------------------- 256x128-tile int8 GEMM -------------------------
// C[M][N] = sw*sx[m] * (Aq[M][K] . Bq[N][K]^T) + bias.
// Tile 256x128, BK=64 bytes, 512 threads = 8 waves (4M x 2N), wave out 64x64.
// LDS per buffer: A 256x64B (16 KB) + B 128x64B (8 KB), x2 = 48 KB.
// Byte-geometry identical to the bf16 champion: staging 3 async16/thread,
// wave-uniform dests, source pre-swizzled 16B-unit ^= ((row>>1)&3); reads
// use the same XOR (measured 0 bank conflicts). Per step: frags, 16 MFMA
// (i32_16x16x64_i8), vmcnt(0), s_barrier; 2 blocks/CU desync hides drain.
__global__ __launch_bounds__(512, 4) void gemm2(const char* __restrict__ A,
                                                const char* __restrict__ B,
                                                const float* __restrict__ bias,
                                                const float* __restrict__ sxp,
                                                const float* __restrict__ swp,
                                                float* __restrict__ C) {
  __shared__ __align__(16) char As[2][16384];  // [buf][256 rows x 64 B]
  __shared__ __align__(16) char Bs[2][8192];   // [buf][128 rows x 64 B]

  const int tid  = threadIdx.x;
  const int wid  = tid >> 6;
  const int lane = tid & 63;
  const int wm = wid >> 1, wn = wid & 1;
  const int l15 = lane & 15;

  // bijective XCD-aware swizzle (m204)
  const int nwg = gridDim.x, bid = blockIdx.x;
  const int q = nwg >> 3, r = nwg & 7;
  const int xcd = bid & 7, sub = bid >> 3;
  const int swz = (xcd < r ? xcd * (q + 1) : r * (q + 1) + (xcd - r) * q) + sub;
  const int gn = N_DIM / 128;          // 32
  const int bm = swz / gn, bn = swz % gn;

  // ---- staging: thread tid loads 16B-unit tid of A-low (rows 0..127),
  // A-high (rows 128..255, LDS byte 8192+), B (rows 0..127). row = tid>>2;
  // source byte-unit pre-swizzled by ((row>>1)&3)<<4.
  const int srow = tid >> 2;
  const int seu  = ((tid & 3) * 16) ^ (((srow >> 1) & 3) << 4);
  const char* gA0 = A + (size_t)(bm * 256 + srow) * K_DIM + seu;
  const char* gA1 = gA0 + (size_t)128 * K_DIM;
  const char* gB  = B + (size_t)(bn * 128 + srow) * K_DIM + seu;
  const int wbase = wid * 1024;  // wave-uniform LDS byte base (64 lanes x 16B)

  // ---- fragment read offsets (read-side XOR matches store swizzle):
  //   16B-unit = (lane>>4) ^ ((row>>1)&3), row = <mult of 16> + l15
  const int esw  = ((lane >> 4) * 16) ^ (((l15 >> 1) & 3) << 4);
  const int aOff = (wm * 64 + l15) * 64 + esw;
  const int bOff = (wn * 64 + l15) * 64 + esw;

  i32x4 acc[4][4];
#pragma unroll
  for (int i = 0; i < 4; ++i)
#pragma unroll
    for (int j = 0; j < 4; ++j) acc[i][j] = (i32x4){0, 0, 0, 0};

  i32x4 af[4], bfr[4];

#define STAGE_(b, kt)                               \
  do {                                              \
    async16(gA0 + (kt), &As[b][wbase]);             \
    async16(gA1 + (kt), &As[b][8192 + wbase]);      \
    async16(gB + (kt), &Bs[b][wbase]);              \
  } while (0)
#define LDFRAG_(b)                                                   \
  do {                                                               \
    _Pragma("unroll") for (int m_ = 0; m_ < 4; ++m_)                 \
        af[m_] = *(const i32x4*)&As[b][aOff + m_ * 1024];            \
    _Pragma("unroll") for (int n_ = 0; n_ < 4; ++n_)                 \
        bfr[n_] = *(const i32x4*)&Bs[b][bOff + n_ * 1024];           \
  } while (0)
#define MM_()                                                        \
  do {                                                               \
    _Pragma("unroll") for (int m_ = 0; m_ < 4; ++m_)                 \
        _Pragma("unroll") for (int n_ = 0; n_ < 4; ++n_)             \
            acc[m_][n_] = __builtin_amdgcn_mfma_i32_16x16x64_i8(     \
                af[m_], bfr[n_], acc[m_][n_], 0, 0, 0);              \
  } while (0)
#define VMW0 asm volatile("s_waitcnt vmcnt(0)" ::: "memory")
#define BAR  __builtin_amdgcn_s_barrier()

  // prologue: stage step 0 into buf 0
  STAGE_(0, 0);
  VMW0;
  BAR;

  // 63 pipelined steps: 31 x (buf0, buf1) + 1 x buf0; tail reads buf1.
  for (int t = 0; t < NSTEP - 2; t += 2) {
    STAGE_(1, (t + 1) * 64);
    LDFRAG_(0); MM_();
    VMW0; BAR;
    STAGE_(0, (t + 2) * 64);
    LDFRAG_(1); MM_();
    VMW0; BAR;
  }
  STAGE_(1, (NSTEP - 1) * 64);
  LDFRAG_(0); MM_();
  VMW0; BAR;
  LDFRAG_(1); MM_();

#undef STAGE_
#undef LDFRAG_
#undef MM_
#undef VMW0
#undef BAR

  // C write: C/D layout col = lane&15, row = (lane>>4)*4 + reg (shape-
  // determined, dtype-independent). y = sw*sx[row]*acc + bias[col].
  const float sw = *swp;
  float bb[4];
#pragma unroll
  for (int n = 0; n < 4; ++n) bb[n] = bias[bn * 128 + wn * 64 + n * 16 + l15];

  float* Cp = C + (size_t)(bm * 256 + wm * 64) * N_DIM + bn * 128 + wn * 64;
  const int rbase = (lane >> 4) * 4;
#pragma unroll
  for (int mi = 0; mi < 4; ++mi)
#pragma unroll
    for (int rr = 0; rr < 4; ++rr) {
      const int grow = bm * 256 + wm * 64 + mi * 16 + rbase + rr;
      const float s = sxp[grow] * sw;
      float* cr = Cp + (size_t)(mi * 16 + rbase + rr) * N_DIM;
#pragma unroll
      for (int n = 0; n < 4; ++n)
        cr[n * 16 + l15] = (float)acc[mi][n][rr] * s + bb[n];
    }
}

// --------------------------- naive fallback (ws too small) ------------------
__global__ void naive_kernel(const float* __restrict__ x,
                             const float* __restrict__ cent,
                             const int* __restrict__ labels,
                             const float* __restrict__ bias,
                             float* __restrict__ out, int M) {
  __shared__ float cb[256];
  if (threadIdx.x < 256) cb[threadIdx.x] = cent[threadIdx.x];
  __syncthreads();
  long o = (long)blockIdx.x * blockDim.x + threadIdx.x;
  if (o >= (long)M * N_DIM) return;
  int n = (int)(o % N_DIM);
  long m = o / N_DIM;
  const float* xr = x + m * K_DIM;
  const int* lr = labels + (long)n * K_DIM;
  float s = 0.f;
  for (int k = 0; k < K_DIM; ++k) s += xr[k] * cb[lr[k]];
  out[o] = s + bias[n];
}

// ---------------------------------------------------------------------------
extern "C" void kernel_launch(void* const* d_in, const int* in_sizes, int n_in,
                              void* d_out, int out_size, void* d_ws, size_t ws_size,
                              hipStream_t stream) {
  const float* x      = (const float*)d_in[0];
  const float* cent   = (const float*)d_in[1];
  const int*   labels = (const int*)d_in[2];
  const float* bias   = (const float*)d_in[3];
  float* out = (float*)d_out;

  const int xN = in_sizes[0];      // M*K
  const int M  = xN / K_DIM;       // 8192
  const int wN = in_sizes[2];      // N*K

  const size_t need = (size_t)wN + (size_t)xN + (size_t)M * 4 + 64;  // ~48 MB
  if (ws_size < need || (M % 256) != 0) {
    long total = (long)M * N_DIM;
    int blocks = (int)((total + 255) / 256);
    naive_kernel<<<blocks, 256, 0, stream>>>(x, cent, labels, bias, out, M);
    return;
  }

  char*  wq  = (char*)d_ws;                 // [N][K] int8
  char*  xq  = wq + (size_t)wN;             // [M][K] int8
  float* sx  = (float*)(xq + (size_t)xN);   // [M] row scales
  float* swp = sx + M;                      // W scale

  quant_w<<<2048, 256, 0, stream>>>(labels, cent, wq, swp, wN);
  quant_x<<<M, 256, 0, stream>>>(x, xq, sx);

  const int grid = (M / 256) * (N_DIM / 128);  // 1024
  gemm2<<<grid, 512, 0, stream>>>(xq, wq, bias, sx, swp, out);
}